// Round 1
// baseline (74.152 us; speedup 1.0000x reference)
//
#include <hip/hip_runtime.h>

#define NPED 4096
#define SPLIT 32            // j-dimension splits
#define JC (NPED / SPLIT)   // 128 j's per chunk
#define BI 256              // i's per block (= blockDim)
#define EPSF 1e-8f
#define DTF 0.4f
#define INV_MASS (1.0f/60.0f)
// mag = 10 * exp((0.6 - dist)/0.71) = exp2( C0 + C1*dist )
#define C1f (-2.0319648463225964f)   // -log2(e)/0.71
#define C0f (4.54110700268092f)      // log2(10) + 0.6*log2(e)/0.71
#define NLOG2E (-1.4426950408889634f)

__device__ __forceinline__ float rsqf(float x) { return __builtin_amdgcn_rsqf(x); }
__device__ __forceinline__ float ex2(float x)  { return __builtin_amdgcn_exp2f(x); }

// ---- Kernel A: O(N^2) pairwise repulsion, partial sums per j-split ----
__global__ __launch_bounds__(BI) void forces_kernel(const float4* __restrict__ state,
                                                    float2* __restrict__ part) {
    __shared__ float2 spos[JC];
    const int t  = threadIdx.x;
    const int ib = blockIdx.x;   // i-block 0..15
    const int s  = blockIdx.y;   // j-split 0..31
    if (t < JC) {
        float4 r = state[s * JC + t];
        spos[t] = make_float2(r.x, r.y);
    }
    const int i = ib * BI + t;
    float4 me = state[i];
    __syncthreads();
    const float xi = me.x, yi = me.y;
    float fx = 0.f, fy = 0.f;
    #pragma unroll 8
    for (int j = 0; j < JC; ++j) {
        float2 pj = spos[j];
        float dx = xi - pj.x;
        float dy = yi - pj.y;
        float d2 = fmaf(dx, dx, fmaf(dy, dy, EPSF));
        float inv = rsqf(d2);           // 1/dist  (dist = sqrt(d2))
        float dist = d2 * inv;
        float w = ex2(fmaf(dist, C1f, C0f)) * inv;   // mag/dist
        // j==i contributes exactly 0 because dx=dy=0 (bitwise identical loads)
        fx = fmaf(w, dx, fx);
        fy = fmaf(w, dy, fy);
    }
    part[s * NPED + i] = make_float2(fx, fy);
}

// ---- Kernel B: reduce splits, attraction, integrate, clamp, write output+stacked ----
__global__ __launch_bounds__(256) void integrate_kernel(const float4* __restrict__ state,
                                                        const float2* __restrict__ goal,
                                                        const float4* __restrict__ stk,
                                                        const float2* __restrict__ part,
                                                        float* __restrict__ out) {
    const int i = blockIdx.x * 256 + threadIdx.x;
    float fx = 0.f, fy = 0.f;
    #pragma unroll
    for (int s = 0; s < SPLIT; ++s) {
        float2 v = part[s * NPED + i];
        fx += v.x; fy += v.y;
    }
    fx *= INV_MASS; fy *= INV_MASS;          // rf
    float4 st = state[i];
    float2 g  = goal[i];
    float tx = g.x - st.x, ty = g.y - st.y;
    float invg = rsqf(fmaf(tx, tx, fmaf(ty, ty, EPSF)));
    float Fx = fx + 2.f * fmaf(tx, invg, -st.z);   // rf + af
    float Fy = fy + 2.f * fmaf(ty, invg, -st.w);
    float npx = fmaf(0.08f, Fx, fmaf(DTF, st.z, st.x));  // 0.5*DT^2 = 0.08
    float npy = fmaf(0.08f, Fy, fmaf(DTF, st.w, st.y));
    float nvx = fmaf(DTF, Fx, st.z);
    float nvy = fmaf(DTF, Fy, st.w);
    float invs = rsqf(fmaf(nvx, nvx, fmaf(nvy, nvy, EPSF)));
    float sc = fminf(1.f, invs);             // min(1, PED_SPEED/spd), PED_SPEED=1
    nvx *= sc; nvy *= sc;
    ((float4*)out)[i] = make_float4(npx, npy, nvx, nvy);
    // stacked = concat(stacked_in, state) at out offset N*4+1 (4B-aligned only)
    float4 sv = stk[i];
    float* o1 = out + (NPED * 4 + 1) + i * 4;
    o1[0] = sv.x; o1[1] = sv.y; o1[2] = sv.z; o1[3] = sv.w;
    float* o2 = o1 + NPED * 4;
    o2[0] = st.x; o2[1] = st.y; o2[2] = st.z; o2[3] = st.w;
}

// ---- Kernel C: cost reduction (single block) ----
__global__ __launch_bounds__(1024) void cost_kernel(const float* __restrict__ state,
                                                    const float* __restrict__ cost_in,
                                                    const float* __restrict__ goal,
                                                    const float* __restrict__ obs,
                                                    float* __restrict__ out) {
    const int t = threadIdx.x;
    const float rx = out[0], ry = out[1];   // robot new pose (written by kernel B)
    float dev = 0.f, blame = 0.f;
    for (int i = 1 + t; i < NPED; i += 1024) {
        float px = out[i * 4 + 0], py = out[i * 4 + 1];
        float ox = obs[i * 4 + 0], oy = obs[i * 4 + 1];
        float dxo = px - ox, dyo = py - oy;
        dev += sqrtf(fmaf(dxo, dxo, fmaf(dyo, dyo, EPSF)));
        float dxr = px - rx, dyr = py - ry;
        float d = sqrtf(fmaf(dxr, dxr, fmaf(dyr, dyr, EPSF)));
        blame += ex2(NLOG2E * d);           // exp(-d)
    }
    #pragma unroll
    for (int off = 32; off > 0; off >>= 1) {
        dev   += __shfl_down(dev, off);
        blame += __shfl_down(blame, off);
    }
    __shared__ float sd[16], sb[16];
    if ((t & 63) == 0) { sd[t >> 6] = dev; sb[t >> 6] = blame; }
    __syncthreads();
    if (t == 0) {
        float D = 0.f, B = 0.f;
        #pragma unroll
        for (int k = 0; k < 16; ++k) { D += sd[k]; B += sb[k]; }
        float gx = goal[0], gy = goal[1];
        float rix = state[0], riy = state[1];
        float a1x = rix - gx, a1y = riy - gy;
        float a2x = rx - gx,  a2y = ry - gy;
        float pg = sqrtf(fmaf(a1x, a1x, fmaf(a1y, a1y, EPSF)))
                 - sqrtf(fmaf(a2x, a2x, fmaf(a2y, a2y, EPSF)));
        out[NPED * 4] = cost_in[0] + 5.f * D + 2.f * B - pg;
    }
}

extern "C" void kernel_launch(void* const* d_in, const int* in_sizes, int n_in,
                              void* d_out, int out_size, void* d_ws, size_t ws_size,
                              hipStream_t stream) {
    const float4* state = (const float4*)d_in[0];   // (N,4)
    const float*  cost  = (const float*)d_in[1];    // (1,)
    const float4* stk   = (const float4*)d_in[2];   // (N,4)
    const float2* goal  = (const float2*)d_in[3];   // (N,2)
    const float*  obs   = (const float*)d_in[4];    // (N,4)
    float* out = (float*)d_out;                     // N*4 | 1 | 2N*4
    float2* part = (float2*)d_ws;                   // SPLIT*N float2 = 1 MiB

    forces_kernel<<<dim3(NPED / BI, SPLIT), BI, 0, stream>>>(state, part);
    integrate_kernel<<<NPED / 256, 256, 0, stream>>>(state, goal, stk, part, out);
    cost_kernel<<<1, 1024, 0, stream>>>((const float*)state, cost,
                                        (const float*)goal, obs, out);
}